// Round 8
// baseline (4521.383 us; speedup 1.0000x reference)
//
#include <hip/hip_runtime.h>
#include <stdint.h>

typedef unsigned short u16;
typedef __bf16 bf16x8 __attribute__((ext_vector_type(8)));
typedef float f32x4 __attribute__((ext_vector_type(4)));

#define K_DIM 4096
#define N_OUT 4096
#define M_ROWS 8192

// ---------- helpers ----------

__device__ __forceinline__ u16 f2bf(float f) {
    uint32_t u = __builtin_bit_cast(uint32_t, f);
    u += 0x7fffu + ((u >> 16) & 1u);
    return (u16)(u >> 16);
}

__device__ __forceinline__ void gload_lds16(const void* g, void* l) {
    __builtin_amdgcn_global_load_lds(
        (const __attribute__((address_space(1))) void*)g,
        (__attribute__((address_space(3))) void*)l,
        16, 0, 0);
}

__device__ __forceinline__ int mask_is_int32(const void* maskp) {
    const uint32_t* u = (const uint32_t*)maskp;
    int ok = 1;
#pragma unroll
    for (int g = 0; g < 16; ++g) ok &= (u[g] <= 1u);
    return ok;
}

// ---------- prep kernels (~70us combined, near BW floor) ----------

__global__ __launch_bounds__(256) void cvt_x_kernel(const float* __restrict__ x,
                                                    u16* __restrict__ xb) {
    size_t t = (size_t)blockIdx.x * 256 + threadIdx.x;
    const float4* p = (const float4*)x + t * 2;
    float4 a = p[0], b = p[1];
    union { u16 u[8]; uint4 v; } o;
    o.u[0] = f2bf(a.x); o.u[1] = f2bf(a.y); o.u[2] = f2bf(a.z); o.u[3] = f2bf(a.w);
    o.u[4] = f2bf(b.x); o.u[5] = f2bf(b.y); o.u[6] = f2bf(b.z); o.u[7] = f2bf(b.w);
    ((uint4*)xb)[t] = o.v;
}

__global__ __launch_bounds__(256) void build_w_kernel(const int* __restrict__ wq,
                                                      const float* __restrict__ qscale,
                                                      const float* __restrict__ qzero,
                                                      const float* __restrict__ theta,
                                                      const void* __restrict__ maskp,
                                                      u16* __restrict__ wb) {
    const int mi32 = mask_is_int32(maskp);
    size_t t = (size_t)blockIdx.x * 256 + threadIdx.x;
    size_t base = t * 8;
    int o = (int)(base >> 12);
    float s = qscale[o], z = qzero[o];

    int4 q0 = ((const int4*)wq)[t * 2];
    int4 q1 = ((const int4*)wq)[t * 2 + 1];
    float4 th0 = ((const float4*)theta)[t * 2];
    float4 th1 = ((const float4*)theta)[t * 2 + 1];

    int mv[8];
    if (mi32) {
        int4 m0 = ((const int4*)maskp)[t * 2];
        int4 m1 = ((const int4*)maskp)[t * 2 + 1];
        mv[0] = m0.x; mv[1] = m0.y; mv[2] = m0.z; mv[3] = m0.w;
        mv[4] = m1.x; mv[5] = m1.y; mv[6] = m1.z; mv[7] = m1.w;
    } else {
        uint2 mm = ((const uint2*)maskp)[t];
#pragma unroll
        for (int j = 0; j < 4; ++j) mv[j] = (mm.x >> (8 * j)) & 0xff;
#pragma unroll
        for (int j = 0; j < 4; ++j) mv[4 + j] = (mm.y >> (8 * j)) & 0xff;
    }

    float w[8];
    w[0] = mv[0] ? ((float)q0.x - z) * s : th0.x;
    w[1] = mv[1] ? ((float)q0.y - z) * s : th0.y;
    w[2] = mv[2] ? ((float)q0.z - z) * s : th0.z;
    w[3] = mv[3] ? ((float)q0.w - z) * s : th0.w;
    w[4] = mv[4] ? ((float)q1.x - z) * s : th1.x;
    w[5] = mv[5] ? ((float)q1.y - z) * s : th1.y;
    w[6] = mv[6] ? ((float)q1.z - z) * s : th1.z;
    w[7] = mv[7] ? ((float)q1.w - z) * s : th1.w;

    union { u16 u[8]; uint4 v; } ob;
#pragma unroll
    for (int j = 0; j < 8; ++j) ob.u[j] = f2bf(w[j]);
    ((uint4*)wb)[t] = ob.v;
}

// ---------- 256x256 GEMM, 16x16x32, read-ahead + 2 blocks/CU (r8) ----------
//
// Change vs r7: LDS halved 128->64 KiB (2 planes/operand instead of 4; plane =
// K-step & 1, K-step = 32). 2 blocks/CU -> cross-block TLP fills barrier/wait
// stalls (the 26% r7 couldn't hide). Read/write LDS patterns, swizzle, read-ahead
// register pipeline identical to r7 (frozen: only empirically 0-conflict layout).
// Per K-step s (plane p=s&1, bf set = s&1):
//   PhA: read-ahead A-MH1(s, p); MFMA16(MH0, afA, bfCur); BAR
//   PhB: stage(s+2 -> p) [4 gloads]; vmcnt(4) [drains stage(s+1); stage(s+2)
//        stays in flight -> counted, never 0]; read-ahead A-MH0(s+1, p^1) +
//        B(s+1, p^1); MFMA16(MH1, afB, bfCur); BAR
// Hazards: stage(s+2) issued 1 barrier after plane p's last reader (PhA) --
// same discipline as r3/r7, validated 6 rounds; data ready 2 phases before use,
// vmcnt(4) covers. Tail wrap (&127) stages dead data, read into unused regs.
// LDS swizzle = r3: phys_slot = log_slot ^ ((row>>1)&3); write via pre-swizzled
// global source chunk (l&3)^((l>>3)&3). 0 bank conflicts (r3/r7 measured).

__global__ __launch_bounds__(512, 4) void gemm8_kernel(const u16* __restrict__ xb,
                                                       const u16* __restrict__ wb,
                                                       const float* __restrict__ bias,
                                                       float* __restrict__ out) {
    __shared__ u16 lds[32768];  // 64 KiB: A planes [0,16384), B planes [16384,32768)

    const int tid = threadIdx.x;
    const int lane = tid & 63, wave = tid >> 6;
    const int wm = wave >> 2, wn = wave & 3;
    const int n0 = blockIdx.x * 256;
    const int m0 = blockIdx.y * 256;

    // fragment-read addressing (u16 units) — r3 proven pattern
    const int a_r = wm * 128 + (lane & 15);
    const int b_r = wn * 64 + (lane & 15);
    const int rslot = ((lane >> 4) ^ ((lane >> 1) & 3)) * 8;

    // stage addressing: wave w instr i covers chunk c=w*2+i = rows [c*16,+16)
    const int ch0 = wave * 2, ch1 = ch0 + 1;
    const int sRow = lane >> 2;
    const int sK = (((lane & 3) ^ ((lane >> 3) & 3)) * 8);
    const u16* gA0 = xb + (size_t)(m0 + ch0 * 16 + sRow) * K_DIM + sK;
    const u16* gA1 = xb + (size_t)(m0 + ch1 * 16 + sRow) * K_DIM + sK;
    const u16* gB0 = wb + (size_t)(n0 + ch0 * 16 + sRow) * K_DIM + sK;
    const u16* gB1 = wb + (size_t)(n0 + ch1 * 16 + sRow) * K_DIM + sK;

    f32x4 acc[8][4];
    const f32x4 zero = {0.f, 0.f, 0.f, 0.f};
#pragma unroll
    for (int m = 0; m < 8; ++m)
#pragma unroll
        for (int n = 0; n < 4; ++n) acc[m][n] = zero;

    // double-buffered fragment register sets (static names, rule #20)
    bf16x8 afA0, afA1, afA2, afA3, afB0, afB1, afB2, afB3;
    bf16x8 bfA0, bfA1, bfA2, bfA3, bfB0, bfB1, bfB2, bfB3;

#define SA(P, ST) { \
    const size_t kofs = (size_t)(((ST) & 127) * 32); \
    const int pl = (P) * 8192; \
    gload_lds16(gA0 + kofs, &lds[pl + ch0 * 512]); \
    gload_lds16(gA1 + kofs, &lds[pl + ch1 * 512]); }
#define SB(P, ST) { \
    const size_t kofs = (size_t)(((ST) & 127) * 32); \
    const int pl = 16384 + (P) * 8192; \
    gload_lds16(gB0 + kofs, &lds[pl + ch0 * 512]); \
    gload_lds16(gB1 + kofs, &lds[pl + ch1 * 512]); }
#define DAx(S, P, MH) { \
    const int pa = (P) * 8192 + (a_r + (MH) * 64) * 32 + rslot; \
    af##S##0 = *(const bf16x8*)&lds[pa]; \
    af##S##1 = *(const bf16x8*)&lds[pa + 512]; \
    af##S##2 = *(const bf16x8*)&lds[pa + 1024]; \
    af##S##3 = *(const bf16x8*)&lds[pa + 1536]; }
#define DBx(S, P) { \
    const int pb = 16384 + (P) * 8192 + b_r * 32 + rslot; \
    bf##S##0 = *(const bf16x8*)&lds[pb]; \
    bf##S##1 = *(const bf16x8*)&lds[pb + 512]; \
    bf##S##2 = *(const bf16x8*)&lds[pb + 1024]; \
    bf##S##3 = *(const bf16x8*)&lds[pb + 1536]; }
#define MF(A, B, C) __builtin_amdgcn_mfma_f32_16x16x32_bf16(A, B, C, 0, 0, 0)
#define MFMA16(MH, AS, BS) { \
    __builtin_amdgcn_s_setprio(1); \
    acc[(MH)*4+0][0] = MF(af##AS##0, bf##BS##0, acc[(MH)*4+0][0]); \
    acc[(MH)*4+0][1] = MF(af##AS##0, bf##BS##1, acc[(MH)*4+0][1]); \
    acc[(MH)*4+0][2] = MF(af##AS##0, bf##BS##2, acc[(MH)*4+0][2]); \
    acc[(MH)*4+0][3] = MF(af##AS##0, bf##BS##3, acc[(MH)*4+0][3]); \
    acc[(MH)*4+1][0] = MF(af##AS##1, bf##BS##0, acc[(MH)*4+1][0]); \
    acc[(MH)*4+1][1] = MF(af##AS##1, bf##BS##1, acc[(MH)*4+1][1]); \
    acc[(MH)*4+1][2] = MF(af##AS##1, bf##BS##2, acc[(MH)*4+1][2]); \
    acc[(MH)*4+1][3] = MF(af##AS##1, bf##BS##3, acc[(MH)*4+1][3]); \
    acc[(MH)*4+2][0] = MF(af##AS##2, bf##BS##0, acc[(MH)*4+2][0]); \
    acc[(MH)*4+2][1] = MF(af##AS##2, bf##BS##1, acc[(MH)*4+2][1]); \
    acc[(MH)*4+2][2] = MF(af##AS##2, bf##BS##2, acc[(MH)*4+2][2]); \
    acc[(MH)*4+2][3] = MF(af##AS##2, bf##BS##3, acc[(MH)*4+2][3]); \
    acc[(MH)*4+3][0] = MF(af##AS##3, bf##BS##0, acc[(MH)*4+3][0]); \
    acc[(MH)*4+3][1] = MF(af##AS##3, bf##BS##1, acc[(MH)*4+3][1]); \
    acc[(MH)*4+3][2] = MF(af##AS##3, bf##BS##2, acc[(MH)*4+3][2]); \
    acc[(MH)*4+3][3] = MF(af##AS##3, bf##BS##3, acc[(MH)*4+3][3]); \
    __builtin_amdgcn_s_setprio(0); }
#define BAR() __builtin_amdgcn_s_barrier()
#define SCHED0() __builtin_amdgcn_sched_barrier(0)
#define VMW4() asm volatile("s_waitcnt vmcnt(4)" ::: "memory")

    // one K-step (2 phases). P = plane = step&1; BC = bf set of this step,
    // BN = bf set of next step; ST2 = step+2 (stage target).
#define STEP(P, BC, BN, ST2) { \
    /* PhA */ \
    DAx(B, P, 1); \
    MFMA16(0, A, BC); SCHED0(); BAR(); \
    /* PhB */ \
    SA(P, ST2); SB(P, ST2); \
    VMW4(); \
    DAx(A, (P) ^ 1, 0); DBx(BN, (P) ^ 1); \
    MFMA16(1, B, BC); SCHED0(); BAR(); }

    // prologue: stage steps 0,1; wait step0; prefetch step0 MH0 fragments
    SA(0, 0); SB(0, 0);
    SA(1, 1); SB(1, 1);
    VMW4();
    BAR();
    DAx(A, 0, 0); DBx(A, 0);

#pragma unroll 1
    for (int j = 0; j < 32; ++j) {
        const int s = 4 * j;
        STEP(0, A, B, s + 2);   // step s   (plane 0, bfA)
        STEP(1, B, A, s + 3);   // step s+1 (plane 1, bfB)
        STEP(0, A, B, s + 4);   // step s+2 (plane 0, bfA)
        STEP(1, B, A, s + 5);   // step s+3 (plane 1, bfB)
    }

    // drain trailing prefetches so no gload lands in deallocated LDS
    asm volatile("s_waitcnt vmcnt(0)" ::: "memory");

    // epilogue: C/D layout col=lane&15, row=(lane>>4)*4+reg
    const int rowBase = m0 + wm * 128 + ((lane >> 4) << 2);
    const int colBase = n0 + wn * 64 + (lane & 15);
#pragma unroll
    for (int n = 0; n < 4; ++n) {
        const int col = colBase + n * 16;
        const float bv = bias[col];
#pragma unroll
        for (int m = 0; m < 8; ++m) {
            const f32x4 v = acc[m][n];
            float* o = out + (size_t)(rowBase + m * 16) * N_OUT + col;
            o[0] = v[0] + bv;
            o[N_OUT] = v[1] + bv;
            o[2 * N_OUT] = v[2] + bv;
            o[3 * N_OUT] = v[3] + bv;
        }
    }
#undef SA
#undef SB
#undef DAx
#undef DBx
#undef MF
#undef MFMA16
#undef BAR
#undef SCHED0
#undef VMW4
#undef STEP
}

// ---------- correct-but-slow fallback (only if ws too small) ----------

__global__ __launch_bounds__(256) void fallback_kernel(const float* __restrict__ x,
                                                       const int* __restrict__ wq,
                                                       const float* __restrict__ qscale,
                                                       const float* __restrict__ qzero,
                                                       const float* __restrict__ theta,
                                                       const void* __restrict__ maskp,
                                                       const float* __restrict__ bias,
                                                       float* __restrict__ out) {
    __shared__ float xs[64][17];
    __shared__ float wsh[64][17];
    const int mi32 = mask_is_int32(maskp);
    const int n0 = blockIdx.x * 64, m0 = blockIdx.y * 64;
    const int t = threadIdx.x;
    const int tr = t >> 4, tc = t & 15;
    float acc[4][4] = {};

    for (int k0 = 0; k0 < K_DIM; k0 += 16) {
#pragma unroll
        for (int j = 0; j < 4; ++j) {
            int e = t * 4 + j;
            int r = e >> 4, c = e & 15;
            xs[r][c] = x[(size_t)(m0 + r) * K_DIM + k0 + c];
            int o = n0 + r;
            size_t idx = (size_t)o * K_DIM + k0 + c;
            float dq = ((float)wq[idx] - qzero[o]) * qscale[o];
            int mv = mi32 ? ((const int*)maskp)[idx] : ((const unsigned char*)maskp)[idx];
            wsh[r][c] = mv ? dq : theta[idx];
        }
        __syncthreads();
#pragma unroll
        for (int kk = 0; kk < 16; ++kk) {
            float a4[4], b4[4];
#pragma unroll
            for (int i = 0; i < 4; ++i) a4[i] = xs[tr * 4 + i][kk];
#pragma unroll
            for (int i = 0; i < 4; ++i) b4[i] = wsh[tc * 4 + i][kk];
#pragma unroll
            for (int i = 0; i < 4; ++i)
#pragma unroll
                for (int j = 0; j < 4; ++j) acc[i][j] += a4[i] * b4[j];
        }
        __syncthreads();
    }
#pragma unroll
    for (int i = 0; i < 4; ++i)
#pragma unroll
        for (int j = 0; j < 4; ++j)
            out[(size_t)(m0 + tr * 4 + i) * N_OUT + n0 + tc * 4 + j] =
                acc[i][j] + bias[n0 + tc * 4 + j];
}

// ---------- launch ----------

extern "C" void kernel_launch(void* const* d_in, const int* in_sizes, int n_in,
                              void* d_out, int out_size, void* d_ws, size_t ws_size,
                              hipStream_t stream) {
    const float* x      = (const float*)d_in[0];
    const int*   wq     = (const int*)d_in[1];
    const float* qscale = (const float*)d_in[2];
    const float* qzero  = (const float*)d_in[3];
    const float* theta  = (const float*)d_in[4];
    const void*  mask   = d_in[5];
    const float* bias   = (const float*)d_in[6];
    float* out = (float*)d_out;

    const size_t xb_bytes = (size_t)M_ROWS * K_DIM * 2;
    const size_t wb_bytes = (size_t)N_OUT * K_DIM * 2;

    if (ws_size >= xb_bytes + wb_bytes) {
        u16* xb = (u16*)d_ws;
        u16* wb = (u16*)((char*)d_ws + xb_bytes);
        cvt_x_kernel<<<16384, 256, 0, stream>>>(x, xb);
        build_w_kernel<<<8192, 256, 0, stream>>>(wq, qscale, qzero, theta, mask, wb);
        dim3 grid(N_OUT / 256, M_ROWS / 256);
        gemm8_kernel<<<grid, 512, 0, stream>>>(xb, wb, bias, out);
    } else {
        dim3 grid(N_OUT / 64, M_ROWS / 64);
        fallback_kernel<<<grid, 256, 0, stream>>>(x, wq, qscale, qzero, theta, mask, bias, out);
    }
}

// Round 9
// 320.596 us; speedup vs baseline: 14.1030x; 14.1030x over previous
//
#include <hip/hip_runtime.h>
#include <stdint.h>

typedef unsigned short u16;
typedef __bf16 bf16x8 __attribute__((ext_vector_type(8)));
typedef float f32x4 __attribute__((ext_vector_type(4)));

#define K_DIM 4096
#define N_OUT 4096
#define M_ROWS 8192

// ---------- helpers ----------

__device__ __forceinline__ u16 f2bf(float f) {
    uint32_t u = __builtin_bit_cast(uint32_t, f);
    u += 0x7fffu + ((u >> 16) & 1u);
    return (u16)(u >> 16);
}

__device__ __forceinline__ void gload_lds16(const void* g, void* l) {
    __builtin_amdgcn_global_load_lds(
        (const __attribute__((address_space(1))) void*)g,
        (__attribute__((address_space(3))) void*)l,
        16, 0, 0);
}

__device__ __forceinline__ int mask_is_int32(const void* maskp) {
    const uint32_t* u = (const uint32_t*)maskp;
    int ok = 1;
#pragma unroll
    for (int g = 0; g < 16; ++g) ok &= (u[g] <= 1u);
    return ok;
}

// ---------- fused prep kernel (r9: one dispatch instead of two) ----------
// blocks [0, 16384): x f32 -> bf16 (8 elems/thread)
// blocks [16384, 24576): W_eff = mask ? (wq - qzero)*qscale : theta -> bf16

__global__ __launch_bounds__(256) void prep_kernel(const float* __restrict__ x,
                                                   u16* __restrict__ xb,
                                                   const int* __restrict__ wq,
                                                   const float* __restrict__ qscale,
                                                   const float* __restrict__ qzero,
                                                   const float* __restrict__ theta,
                                                   const void* __restrict__ maskp,
                                                   u16* __restrict__ wb) {
    if (blockIdx.x < 16384) {
        size_t t = (size_t)blockIdx.x * 256 + threadIdx.x;
        const float4* p = (const float4*)x + t * 2;
        float4 a = p[0], b = p[1];
        union { u16 u[8]; uint4 v; } o;
        o.u[0] = f2bf(a.x); o.u[1] = f2bf(a.y); o.u[2] = f2bf(a.z); o.u[3] = f2bf(a.w);
        o.u[4] = f2bf(b.x); o.u[5] = f2bf(b.y); o.u[6] = f2bf(b.z); o.u[7] = f2bf(b.w);
        ((uint4*)xb)[t] = o.v;
    } else {
        const int mi32 = mask_is_int32(maskp);
        size_t t = (size_t)(blockIdx.x - 16384) * 256 + threadIdx.x;
        size_t base = t * 8;
        int o = (int)(base >> 12);
        float s = qscale[o], z = qzero[o];

        int4 q0 = ((const int4*)wq)[t * 2];
        int4 q1 = ((const int4*)wq)[t * 2 + 1];
        float4 th0 = ((const float4*)theta)[t * 2];
        float4 th1 = ((const float4*)theta)[t * 2 + 1];

        int mv[8];
        if (mi32) {
            int4 m0 = ((const int4*)maskp)[t * 2];
            int4 m1 = ((const int4*)maskp)[t * 2 + 1];
            mv[0] = m0.x; mv[1] = m0.y; mv[2] = m0.z; mv[3] = m0.w;
            mv[4] = m1.x; mv[5] = m1.y; mv[6] = m1.z; mv[7] = m1.w;
        } else {
            uint2 mm = ((const uint2*)maskp)[t];
#pragma unroll
            for (int j = 0; j < 4; ++j) mv[j] = (mm.x >> (8 * j)) & 0xff;
#pragma unroll
            for (int j = 0; j < 4; ++j) mv[4 + j] = (mm.y >> (8 * j)) & 0xff;
        }

        float w[8];
        w[0] = mv[0] ? ((float)q0.x - z) * s : th0.x;
        w[1] = mv[1] ? ((float)q0.y - z) * s : th0.y;
        w[2] = mv[2] ? ((float)q0.z - z) * s : th0.z;
        w[3] = mv[3] ? ((float)q0.w - z) * s : th0.w;
        w[4] = mv[4] ? ((float)q1.x - z) * s : th1.x;
        w[5] = mv[5] ? ((float)q1.y - z) * s : th1.y;
        w[6] = mv[6] ? ((float)q1.z - z) * s : th1.z;
        w[7] = mv[7] ? ((float)q1.w - z) * s : th1.w;

        union { u16 u[8]; uint4 v; } ob;
#pragma unroll
        for (int j = 0; j < 8; ++j) ob.u[j] = f2bf(w[j]);
        ((uint4*)wb)[t] = ob.v;
    }
}

// ---------- 256x256 8-phase GEMM, 16x16x32, read-ahead pipeline (r7 EXACT) ----------
//
// r9 = byte-identical revert to r7 (best measured: 240us, MfmaUtil 55.5%,
// 0 bank conflicts, VGPR 128 @ launch_bounds(512,2)). r8's (512,4) forced a
// 128-reg budget -> 64 arch VGPR + scratch spills -> 17x slowdown. 2 waves/SIMD
// is STRUCTURAL for 256^2 8-wave (acc alone = 128 VGPR/lane); m201/HK run the
// same occupancy. Do not touch launch_bounds or LDS size again.
// Pipeline: ds_reads issued ONE PHASE AHEAD into alternating register sets
// (afA/afB, bfA/bfB); MFMA consumes regs whose lgkm completed during the
// previous phase's MFMA. One barrier per phase; vmcnt(4) at P1/P3/P5/P7
// (counted, never 0; each drains the stage-pair from 4 phases earlier, with
// >=1 barrier between drain and read). LDS swizzle = r3 proven: phys_slot =
// log_slot ^ ((row>>1)&3); write via pre-swizzled global source chunk
// (l&3)^((l>>3)&3) (both-sides involution, rule #21).

__global__ __launch_bounds__(512, 2) void gemm8_kernel(const u16* __restrict__ xb,
                                                       const u16* __restrict__ wb,
                                                       const float* __restrict__ bias,
                                                       float* __restrict__ out) {
    __shared__ u16 lds[65536];  // 128 KiB: A planes [0,32768), B planes [32768,65536)

    const int tid = threadIdx.x;
    const int lane = tid & 63, wave = tid >> 6;
    const int wm = wave >> 2, wn = wave & 3;
    const int n0 = blockIdx.x * 256;
    const int m0 = blockIdx.y * 256;

    // fragment-read addressing (u16 units) — r3 proven pattern
    const int a_r = wm * 128 + (lane & 15);
    const int b_r = wn * 64 + (lane & 15);
    const int rslot = ((lane >> 4) ^ ((lane >> 1) & 3)) * 8;

    // stage addressing: wave w instr i covers chunk c=w*2+i = rows [c*16,+16)
    const int ch0 = wave * 2, ch1 = ch0 + 1;
    const int sRow = lane >> 2;
    const int sK = (((lane & 3) ^ ((lane >> 3) & 3)) * 8);
    const u16* gA0 = xb + (size_t)(m0 + ch0 * 16 + sRow) * K_DIM + sK;
    const u16* gA1 = xb + (size_t)(m0 + ch1 * 16 + sRow) * K_DIM + sK;
    const u16* gB0 = wb + (size_t)(n0 + ch0 * 16 + sRow) * K_DIM + sK;
    const u16* gB1 = wb + (size_t)(n0 + ch1 * 16 + sRow) * K_DIM + sK;

    f32x4 acc[8][4];
    const f32x4 zero = {0.f, 0.f, 0.f, 0.f};
#pragma unroll
    for (int m = 0; m < 8; ++m)
#pragma unroll
        for (int n = 0; n < 4; ++n) acc[m][n] = zero;

    // double-buffered fragment register sets (static names, rule #20)
    bf16x8 afA0, afA1, afA2, afA3, afB0, afB1, afB2, afB3;
    bf16x8 bfA0, bfA1, bfA2, bfA3, bfB0, bfB1, bfB2, bfB3;

#define SA(BUF, KH, KT) { \
    const size_t kofs = (size_t)((KT) * 64 + (KH) * 32); \
    const int pl = ((BUF) * 2 + (KH)) * 8192; \
    gload_lds16(gA0 + kofs, &lds[pl + ch0 * 512]); \
    gload_lds16(gA1 + kofs, &lds[pl + ch1 * 512]); }
#define SB(BUF, KH, KT) { \
    const size_t kofs = (size_t)((KT) * 64 + (KH) * 32); \
    const int pl = 32768 + ((BUF) * 2 + (KH)) * 8192; \
    gload_lds16(gB0 + kofs, &lds[pl + ch0 * 512]); \
    gload_lds16(gB1 + kofs, &lds[pl + ch1 * 512]); }
#define DAx(S, BUF, KS, MH) { \
    const int pa = ((BUF) * 2 + (KS)) * 8192 + (a_r + (MH) * 64) * 32 + rslot; \
    af##S##0 = *(const bf16x8*)&lds[pa]; \
    af##S##1 = *(const bf16x8*)&lds[pa + 512]; \
    af##S##2 = *(const bf16x8*)&lds[pa + 1024]; \
    af##S##3 = *(const bf16x8*)&lds[pa + 1536]; }
#define DBx(S, BUF, KS) { \
    const int pb = 32768 + ((BUF) * 2 + (KS)) * 8192 + b_r * 32 + rslot; \
    bf##S##0 = *(const bf16x8*)&lds[pb]; \
    bf##S##1 = *(const bf16x8*)&lds[pb + 512]; \
    bf##S##2 = *(const bf16x8*)&lds[pb + 1024]; \
    bf##S##3 = *(const bf16x8*)&lds[pb + 1536]; }
#define MF(A, B, C) __builtin_amdgcn_mfma_f32_16x16x32_bf16(A, B, C, 0, 0, 0)
#define MFMA16(MH, AS, BS) { \
    __builtin_amdgcn_s_setprio(1); \
    acc[(MH)*4+0][0] = MF(af##AS##0, bf##BS##0, acc[(MH)*4+0][0]); \
    acc[(MH)*4+0][1] = MF(af##AS##0, bf##BS##1, acc[(MH)*4+0][1]); \
    acc[(MH)*4+0][2] = MF(af##AS##0, bf##BS##2, acc[(MH)*4+0][2]); \
    acc[(MH)*4+0][3] = MF(af##AS##0, bf##BS##3, acc[(MH)*4+0][3]); \
    acc[(MH)*4+1][0] = MF(af##AS##1, bf##BS##0, acc[(MH)*4+1][0]); \
    acc[(MH)*4+1][1] = MF(af##AS##1, bf##BS##1, acc[(MH)*4+1][1]); \
    acc[(MH)*4+1][2] = MF(af##AS##1, bf##BS##2, acc[(MH)*4+1][2]); \
    acc[(MH)*4+1][3] = MF(af##AS##1, bf##BS##3, acc[(MH)*4+1][3]); \
    acc[(MH)*4+2][0] = MF(af##AS##2, bf##BS##0, acc[(MH)*4+2][0]); \
    acc[(MH)*4+2][1] = MF(af##AS##2, bf##BS##1, acc[(MH)*4+2][1]); \
    acc[(MH)*4+2][2] = MF(af##AS##2, bf##BS##2, acc[(MH)*4+2][2]); \
    acc[(MH)*4+2][3] = MF(af##AS##2, bf##BS##3, acc[(MH)*4+2][3]); \
    acc[(MH)*4+3][0] = MF(af##AS##3, bf##BS##0, acc[(MH)*4+3][0]); \
    acc[(MH)*4+3][1] = MF(af##AS##3, bf##BS##1, acc[(MH)*4+3][1]); \
    acc[(MH)*4+3][2] = MF(af##AS##3, bf##BS##2, acc[(MH)*4+3][2]); \
    acc[(MH)*4+3][3] = MF(af##AS##3, bf##BS##3, acc[(MH)*4+3][3]); \
    __builtin_amdgcn_s_setprio(0); }
#define BAR() __builtin_amdgcn_s_barrier()
#define SCHED0() __builtin_amdgcn_sched_barrier(0)
#define VMW4() asm volatile("s_waitcnt vmcnt(4)" ::: "memory")

    // prologue: tile0 full + tile1 khalf0, then prefetch P1's fragments
    SA(0, 0, 0); SB(0, 0, 0);
    SA(0, 1, 0); SB(0, 1, 0);
    SA(1, 0, 1); SB(1, 0, 1);
    asm volatile("s_waitcnt vmcnt(0)" ::: "memory");
    BAR();
    DBx(A, 0, 0); DAx(A, 0, 0, 0);

#pragma unroll 1
    for (int j = 0; j < K_DIM / 128; ++j) {
        const int t1 = 2 * j + 1;
        const int t2 = (2 * j + 2) & 63;
        const int t3 = (2 * j + 3) & 63;
        // P1: consume (afA,bfA) b0k0 MH0; prefetch afB<-b0k0 MH1
        VMW4();
        DAx(B, 0, 0, 1); SA(1, 1, t1);
        MFMA16(0, A, A); SCHED0(); BAR();
        // P2: consume (afB,bfA) MH1; prefetch afA,bfB <- b0k1 MH0
        DAx(A, 0, 1, 0); DBx(B, 0, 1); SB(1, 1, t1);
        MFMA16(1, B, A); SCHED0(); BAR();
        // P3: consume (afA,bfB) b0k1 MH0; prefetch afB<-b0k1 MH1
        VMW4();
        DAx(B, 0, 1, 1); SA(0, 0, t2);
        MFMA16(0, A, B); SCHED0(); BAR();
        // P4: consume (afB,bfB) MH1; prefetch afA,bfA <- b1k0 MH0
        DAx(A, 1, 0, 0); DBx(A, 1, 0); SB(0, 0, t2);
        MFMA16(1, B, B); SCHED0(); BAR();
        // P5: consume (afA,bfA) b1k0 MH0; prefetch afB<-b1k0 MH1
        VMW4();
        DAx(B, 1, 0, 1); SA(0, 1, t2);
        MFMA16(0, A, A); SCHED0(); BAR();
        // P6: consume (afB,bfA) MH1; prefetch afA,bfB <- b1k1 MH0
        DAx(A, 1, 1, 0); DBx(B, 1, 1); SB(0, 1, t2);
        MFMA16(1, B, A); SCHED0(); BAR();
        // P7: consume (afA,bfB) b1k1 MH0; prefetch afB<-b1k1 MH1
        VMW4();
        DAx(B, 1, 1, 1); SA(1, 0, t3);
        MFMA16(0, A, B); SCHED0(); BAR();
        // P8: consume (afB,bfB) MH1; prefetch afA,bfA <- b0k0 (next tile)
        DAx(A, 0, 0, 0); DBx(A, 0, 0); SB(1, 0, t3);
        MFMA16(1, B, B); SCHED0(); BAR();
    }

    // drain trailing prefetches so no gload lands in deallocated LDS
    asm volatile("s_waitcnt vmcnt(0)" ::: "memory");

    // epilogue: C/D layout col=lane&15, row=(lane>>4)*4+reg
    const int rowBase = m0 + wm * 128 + ((lane >> 4) << 2);
    const int colBase = n0 + wn * 64 + (lane & 15);
#pragma unroll
    for (int n = 0; n < 4; ++n) {
        const int col = colBase + n * 16;
        const float bv = bias[col];
#pragma unroll
        for (int m = 0; m < 8; ++m) {
            const f32x4 v = acc[m][n];
            float* o = out + (size_t)(rowBase + m * 16) * N_OUT + col;
            o[0] = v[0] + bv;
            o[N_OUT] = v[1] + bv;
            o[2 * N_OUT] = v[2] + bv;
            o[3 * N_OUT] = v[3] + bv;
        }
    }
#undef SA
#undef SB
#undef DAx
#undef DBx
#undef MF
#undef MFMA16
#undef BAR
#undef SCHED0
#undef VMW4
}

// ---------- correct-but-slow fallback (only if ws too small) ----------

__global__ __launch_bounds__(256) void fallback_kernel(const float* __restrict__ x,
                                                       const int* __restrict__ wq,
                                                       const float* __restrict__ qscale,
                                                       const float* __restrict__ qzero,
                                                       const float* __restrict__ theta,
                                                       const void* __restrict__ maskp,
                                                       const float* __restrict__ bias,
                                                       float* __restrict__ out) {
    __shared__ float xs[64][17];
    __shared__ float wsh[64][17];
    const int mi32 = mask_is_int32(maskp);
    const int n0 = blockIdx.x * 64, m0 = blockIdx.y * 64;
    const int t = threadIdx.x;
    const int tr = t >> 4, tc = t & 15;
    float acc[4][4] = {};

    for (int k0 = 0; k0 < K_DIM; k0 += 16) {
#pragma unroll
        for (int j = 0; j < 4; ++j) {
            int e = t * 4 + j;
            int r = e >> 4, c = e & 15;
            xs[r][c] = x[(size_t)(m0 + r) * K_DIM + k0 + c];
            int o = n0 + r;
            size_t idx = (size_t)o * K_DIM + k0 + c;
            float dq = ((float)wq[idx] - qzero[o]) * qscale[o];
            int mv = mi32 ? ((const int*)maskp)[idx] : ((const unsigned char*)maskp)[idx];
            wsh[r][c] = mv ? dq : theta[idx];
        }
        __syncthreads();
#pragma unroll
        for (int kk = 0; kk < 16; ++kk) {
            float a4[4], b4[4];
#pragma unroll
            for (int i = 0; i < 4; ++i) a4[i] = xs[tr * 4 + i][kk];
#pragma unroll
            for (int i = 0; i < 4; ++i) b4[i] = wsh[tc * 4 + i][kk];
#pragma unroll
            for (int i = 0; i < 4; ++i)
#pragma unroll
                for (int j = 0; j < 4; ++j) acc[i][j] += a4[i] * b4[j];
        }
        __syncthreads();
    }
#pragma unroll
    for (int i = 0; i < 4; ++i)
#pragma unroll
        for (int j = 0; j < 4; ++j)
            out[(size_t)(m0 + tr * 4 + i) * N_OUT + n0 + tc * 4 + j] =
                acc[i][j] + bias[n0 + tc * 4 + j];
}

// ---------- launch ----------

extern "C" void kernel_launch(void* const* d_in, const int* in_sizes, int n_in,
                              void* d_out, int out_size, void* d_ws, size_t ws_size,
                              hipStream_t stream) {
    const float* x      = (const float*)d_in[0];
    const int*   wq     = (const int*)d_in[1];
    const float* qscale = (const float*)d_in[2];
    const float* qzero  = (const float*)d_in[3];
    const float* theta  = (const float*)d_in[4];
    const void*  mask   = d_in[5];
    const float* bias   = (const float*)d_in[6];
    float* out = (float*)d_out;

    const size_t xb_bytes = (size_t)M_ROWS * K_DIM * 2;
    const size_t wb_bytes = (size_t)N_OUT * K_DIM * 2;

    if (ws_size >= xb_bytes + wb_bytes) {
        u16* xb = (u16*)d_ws;
        u16* wb = (u16*)((char*)d_ws + xb_bytes);
        prep_kernel<<<24576, 256, 0, stream>>>(x, xb, wq, qscale, qzero, theta, mask, wb);
        dim3 grid(N_OUT / 256, M_ROWS / 256);
        gemm8_kernel<<<grid, 512, 0, stream>>>(xb, wb, bias, out);
    } else {
        dim3 grid(N_OUT / 64, M_ROWS / 64);
        fallback_kernel<<<grid, 256, 0, stream>>>(x, wq, qscale, qzero, theta, mask, bias, out);
    }
}

// Round 10
// 317.849 us; speedup vs baseline: 14.2250x; 1.0086x over previous
//
#include <hip/hip_runtime.h>
#include <stdint.h>

typedef unsigned short u16;
typedef __bf16 bf16x8 __attribute__((ext_vector_type(8)));
typedef float f32x4 __attribute__((ext_vector_type(4)));

#define K_DIM 4096
#define N_OUT 4096
#define M_ROWS 8192

// ---------- helpers ----------

__device__ __forceinline__ u16 f2bf(float f) {
    uint32_t u = __builtin_bit_cast(uint32_t, f);
    u += 0x7fffu + ((u >> 16) & 1u);
    return (u16)(u >> 16);
}

__device__ __forceinline__ void gload_lds16(const void* g, void* l) {
    __builtin_amdgcn_global_load_lds(
        (const __attribute__((address_space(1))) void*)g,
        (__attribute__((address_space(3))) void*)l,
        16, 0, 0);
}

__device__ __forceinline__ int mask_is_int32(const void* maskp) {
    const uint32_t* u = (const uint32_t*)maskp;
    int ok = 1;
#pragma unroll
    for (int g = 0; g < 16; ++g) ok &= (u[g] <= 1u);
    return ok;
}

// ---------- fused prep kernel (r9; ~75us, at BW floor) ----------
// blocks [0, 16384): x f32 -> bf16 (8 elems/thread)
// blocks [16384, 24576): W_eff = mask ? (wq - qzero)*qscale : theta -> bf16

__global__ __launch_bounds__(256) void prep_kernel(const float* __restrict__ x,
                                                   u16* __restrict__ xb,
                                                   const int* __restrict__ wq,
                                                   const float* __restrict__ qscale,
                                                   const float* __restrict__ qzero,
                                                   const float* __restrict__ theta,
                                                   const void* __restrict__ maskp,
                                                   u16* __restrict__ wb) {
    if (blockIdx.x < 16384) {
        size_t t = (size_t)blockIdx.x * 256 + threadIdx.x;
        const float4* p = (const float4*)x + t * 2;
        float4 a = p[0], b = p[1];
        union { u16 u[8]; uint4 v; } o;
        o.u[0] = f2bf(a.x); o.u[1] = f2bf(a.y); o.u[2] = f2bf(a.z); o.u[3] = f2bf(a.w);
        o.u[4] = f2bf(b.x); o.u[5] = f2bf(b.y); o.u[6] = f2bf(b.z); o.u[7] = f2bf(b.w);
        ((uint4*)xb)[t] = o.v;
    } else {
        const int mi32 = mask_is_int32(maskp);
        size_t t = (size_t)(blockIdx.x - 16384) * 256 + threadIdx.x;
        size_t base = t * 8;
        int o = (int)(base >> 12);
        float s = qscale[o], z = qzero[o];

        int4 q0 = ((const int4*)wq)[t * 2];
        int4 q1 = ((const int4*)wq)[t * 2 + 1];
        float4 th0 = ((const float4*)theta)[t * 2];
        float4 th1 = ((const float4*)theta)[t * 2 + 1];

        int mv[8];
        if (mi32) {
            int4 m0 = ((const int4*)maskp)[t * 2];
            int4 m1 = ((const int4*)maskp)[t * 2 + 1];
            mv[0] = m0.x; mv[1] = m0.y; mv[2] = m0.z; mv[3] = m0.w;
            mv[4] = m1.x; mv[5] = m1.y; mv[6] = m1.z; mv[7] = m1.w;
        } else {
            uint2 mm = ((const uint2*)maskp)[t];
#pragma unroll
            for (int j = 0; j < 4; ++j) mv[j] = (mm.x >> (8 * j)) & 0xff;
#pragma unroll
            for (int j = 0; j < 4; ++j) mv[4 + j] = (mm.y >> (8 * j)) & 0xff;
        }

        float w[8];
        w[0] = mv[0] ? ((float)q0.x - z) * s : th0.x;
        w[1] = mv[1] ? ((float)q0.y - z) * s : th0.y;
        w[2] = mv[2] ? ((float)q0.z - z) * s : th0.z;
        w[3] = mv[3] ? ((float)q0.w - z) * s : th0.w;
        w[4] = mv[4] ? ((float)q1.x - z) * s : th1.x;
        w[5] = mv[5] ? ((float)q1.y - z) * s : th1.y;
        w[6] = mv[6] ? ((float)q1.z - z) * s : th1.z;
        w[7] = mv[7] ? ((float)q1.w - z) * s : th1.w;

        union { u16 u[8]; uint4 v; } ob;
#pragma unroll
        for (int j = 0; j < 8; ++j) ob.u[j] = f2bf(w[j]);
        ((uint4*)wb)[t] = ob.v;
    }
}

// ---------- 256x256 8-phase GEMM, 16x16x32, MFMA-first phases (r10) ----------
//
// = r7/r9 schedule with ONE within-phase reorder: MFMA16 moved to the TOP of
// each phase (before VMW4 / read-ahead / stage). Hazard-equivalent proof:
//  - reads at phase p are covered by the VMW4 at p-2 + intervening barrier
//    (r7-verified coverage); same-phase VMW4 position vs reads is not a
//    correctness constraint, only its phase membership (count bookkeeping)
//    and being before the phase-end barrier.
//  - each phase's prefetch target set is disjoint from that phase's consumed
//    set (P1:consume A,A/write afB ... P8:consume B,B/write afA,bfA - checked).
//  - stage slots (between BAR(p-1) and BAR(p)) unchanged.
// Why: VMW4 at phase top stalled the wave with the MFMA pipe idle whenever the
// 4-phase-old stage pair was still in L2 service; MFMA-first hides that wait
// under the ~310-cyc pipe drain. Rule #18: compiler won't hoist MFMA above an
// asm-volatile wait on its own.
// All else frozen: LDS 128 KiB, launch_bounds(512,2) (r8: (512,4) = spill
// cliff, never again), r3 swizzle (phys_slot = log_slot ^ ((row>>1)&3), write
// via pre-swizzled global chunk (l&3)^((l>>3)&3)), vmcnt(4)@P1/P3/P5/P7.

__global__ __launch_bounds__(512, 2) void gemm8_kernel(const u16* __restrict__ xb,
                                                       const u16* __restrict__ wb,
                                                       const float* __restrict__ bias,
                                                       float* __restrict__ out) {
    __shared__ u16 lds[65536];  // 128 KiB: A planes [0,32768), B planes [32768,65536)

    const int tid = threadIdx.x;
    const int lane = tid & 63, wave = tid >> 6;
    const int wm = wave >> 2, wn = wave & 3;
    const int n0 = blockIdx.x * 256;
    const int m0 = blockIdx.y * 256;

    // fragment-read addressing (u16 units) — r3 proven pattern
    const int a_r = wm * 128 + (lane & 15);
    const int b_r = wn * 64 + (lane & 15);
    const int rslot = ((lane >> 4) ^ ((lane >> 1) & 3)) * 8;

    // stage addressing: wave w instr i covers chunk c=w*2+i = rows [c*16,+16)
    const int ch0 = wave * 2, ch1 = ch0 + 1;
    const int sRow = lane >> 2;
    const int sK = (((lane & 3) ^ ((lane >> 3) & 3)) * 8);
    const u16* gA0 = xb + (size_t)(m0 + ch0 * 16 + sRow) * K_DIM + sK;
    const u16* gA1 = xb + (size_t)(m0 + ch1 * 16 + sRow) * K_DIM + sK;
    const u16* gB0 = wb + (size_t)(n0 + ch0 * 16 + sRow) * K_DIM + sK;
    const u16* gB1 = wb + (size_t)(n0 + ch1 * 16 + sRow) * K_DIM + sK;

    f32x4 acc[8][4];
    const f32x4 zero = {0.f, 0.f, 0.f, 0.f};
#pragma unroll
    for (int m = 0; m < 8; ++m)
#pragma unroll
        for (int n = 0; n < 4; ++n) acc[m][n] = zero;

    // double-buffered fragment register sets (static names, rule #20)
    bf16x8 afA0, afA1, afA2, afA3, afB0, afB1, afB2, afB3;
    bf16x8 bfA0, bfA1, bfA2, bfA3, bfB0, bfB1, bfB2, bfB3;

#define SA(BUF, KH, KT) { \
    const size_t kofs = (size_t)((KT) * 64 + (KH) * 32); \
    const int pl = ((BUF) * 2 + (KH)) * 8192; \
    gload_lds16(gA0 + kofs, &lds[pl + ch0 * 512]); \
    gload_lds16(gA1 + kofs, &lds[pl + ch1 * 512]); }
#define SB(BUF, KH, KT) { \
    const size_t kofs = (size_t)((KT) * 64 + (KH) * 32); \
    const int pl = 32768 + ((BUF) * 2 + (KH)) * 8192; \
    gload_lds16(gB0 + kofs, &lds[pl + ch0 * 512]); \
    gload_lds16(gB1 + kofs, &lds[pl + ch1 * 512]); }
#define DAx(S, BUF, KS, MH) { \
    const int pa = ((BUF) * 2 + (KS)) * 8192 + (a_r + (MH) * 64) * 32 + rslot; \
    af##S##0 = *(const bf16x8*)&lds[pa]; \
    af##S##1 = *(const bf16x8*)&lds[pa + 512]; \
    af##S##2 = *(const bf16x8*)&lds[pa + 1024]; \
    af##S##3 = *(const bf16x8*)&lds[pa + 1536]; }
#define DBx(S, BUF, KS) { \
    const int pb = 32768 + ((BUF) * 2 + (KS)) * 8192 + b_r * 32 + rslot; \
    bf##S##0 = *(const bf16x8*)&lds[pb]; \
    bf##S##1 = *(const bf16x8*)&lds[pb + 512]; \
    bf##S##2 = *(const bf16x8*)&lds[pb + 1024]; \
    bf##S##3 = *(const bf16x8*)&lds[pb + 1536]; }
#define MF(A, B, C) __builtin_amdgcn_mfma_f32_16x16x32_bf16(A, B, C, 0, 0, 0)
#define MFMA16(MH, AS, BS) { \
    __builtin_amdgcn_s_setprio(1); \
    acc[(MH)*4+0][0] = MF(af##AS##0, bf##BS##0, acc[(MH)*4+0][0]); \
    acc[(MH)*4+0][1] = MF(af##AS##0, bf##BS##1, acc[(MH)*4+0][1]); \
    acc[(MH)*4+0][2] = MF(af##AS##0, bf##BS##2, acc[(MH)*4+0][2]); \
    acc[(MH)*4+0][3] = MF(af##AS##0, bf##BS##3, acc[(MH)*4+0][3]); \
    acc[(MH)*4+1][0] = MF(af##AS##1, bf##BS##0, acc[(MH)*4+1][0]); \
    acc[(MH)*4+1][1] = MF(af##AS##1, bf##BS##1, acc[(MH)*4+1][1]); \
    acc[(MH)*4+1][2] = MF(af##AS##1, bf##BS##2, acc[(MH)*4+1][2]); \
    acc[(MH)*4+1][3] = MF(af##AS##1, bf##BS##3, acc[(MH)*4+1][3]); \
    acc[(MH)*4+2][0] = MF(af##AS##2, bf##BS##0, acc[(MH)*4+2][0]); \
    acc[(MH)*4+2][1] = MF(af##AS##2, bf##BS##1, acc[(MH)*4+2][1]); \
    acc[(MH)*4+2][2] = MF(af##AS##2, bf##BS##2, acc[(MH)*4+2][2]); \
    acc[(MH)*4+2][3] = MF(af##AS##2, bf##BS##3, acc[(MH)*4+2][3]); \
    acc[(MH)*4+3][0] = MF(af##AS##3, bf##BS##0, acc[(MH)*4+3][0]); \
    acc[(MH)*4+3][1] = MF(af##AS##3, bf##BS##1, acc[(MH)*4+3][1]); \
    acc[(MH)*4+3][2] = MF(af##AS##3, bf##BS##2, acc[(MH)*4+3][2]); \
    acc[(MH)*4+3][3] = MF(af##AS##3, bf##BS##3, acc[(MH)*4+3][3]); \
    __builtin_amdgcn_s_setprio(0); }
#define BAR() __builtin_amdgcn_s_barrier()
#define SCHED0() __builtin_amdgcn_sched_barrier(0)
#define VMW4() asm volatile("s_waitcnt vmcnt(4)" ::: "memory")

    // prologue: tile0 full + tile1 khalf0, then prefetch P1's fragments
    SA(0, 0, 0); SB(0, 0, 0);
    SA(0, 1, 0); SB(0, 1, 0);
    SA(1, 0, 1); SB(1, 0, 1);
    asm volatile("s_waitcnt vmcnt(0)" ::: "memory");
    BAR();
    DBx(A, 0, 0); DAx(A, 0, 0, 0);

#pragma unroll 1
    for (int j = 0; j < K_DIM / 128; ++j) {
        const int t1 = 2 * j + 1;
        const int t2 = (2 * j + 2) & 63;
        const int t3 = (2 * j + 3) & 63;
        // P1: MFMA (afA,bfA) b0k0 MH0; vmcnt; prefetch afB<-b0k0 MH1
        MFMA16(0, A, A);
        VMW4();
        DAx(B, 0, 0, 1); SA(1, 1, t1);
        SCHED0(); BAR();
        // P2: MFMA (afB,bfA) MH1; prefetch afA,bfB <- b0k1 MH0
        MFMA16(1, B, A);
        DAx(A, 0, 1, 0); DBx(B, 0, 1); SB(1, 1, t1);
        SCHED0(); BAR();
        // P3: MFMA (afA,bfB) b0k1 MH0; vmcnt; prefetch afB<-b0k1 MH1
        MFMA16(0, A, B);
        VMW4();
        DAx(B, 0, 1, 1); SA(0, 0, t2);
        SCHED0(); BAR();
        // P4: MFMA (afB,bfB) MH1; prefetch afA,bfA <- b1k0 MH0
        MFMA16(1, B, B);
        DAx(A, 1, 0, 0); DBx(A, 1, 0); SB(0, 0, t2);
        SCHED0(); BAR();
        // P5: MFMA (afA,bfA) b1k0 MH0; vmcnt; prefetch afB<-b1k0 MH1
        MFMA16(0, A, A);
        VMW4();
        DAx(B, 1, 0, 1); SA(0, 1, t2);
        SCHED0(); BAR();
        // P6: MFMA (afB,bfA) MH1; prefetch afA,bfB <- b1k1 MH0
        MFMA16(1, B, A);
        DAx(A, 1, 1, 0); DBx(B, 1, 1); SB(0, 1, t2);
        SCHED0(); BAR();
        // P7: MFMA (afA,bfB) b1k1 MH0; vmcnt; prefetch afB<-b1k1 MH1
        MFMA16(0, A, B);
        VMW4();
        DAx(B, 1, 1, 1); SA(1, 0, t3);
        SCHED0(); BAR();
        // P8: MFMA (afB,bfB) MH1; prefetch afA,bfA <- b0k0 (next tile)
        MFMA16(1, B, B);
        DAx(A, 0, 0, 0); DBx(A, 0, 0); SB(1, 0, t3);
        SCHED0(); BAR();
    }

    // drain trailing prefetches so no gload lands in deallocated LDS
    asm volatile("s_waitcnt vmcnt(0)" ::: "memory");

    // epilogue: C/D layout col=lane&15, row=(lane>>4)*4+reg
    const int rowBase = m0 + wm * 128 + ((lane >> 4) << 2);
    const int colBase = n0 + wn * 64 + (lane & 15);
#pragma unroll
    for (int n = 0; n < 4; ++n) {
        const int col = colBase + n * 16;
        const float bv = bias[col];
#pragma unroll
        for (int m = 0; m < 8; ++m) {
            const f32x4 v = acc[m][n];
            float* o = out + (size_t)(rowBase + m * 16) * N_OUT + col;
            o[0] = v[0] + bv;
            o[N_OUT] = v[1] + bv;
            o[2 * N_OUT] = v[2] + bv;
            o[3 * N_OUT] = v[3] + bv;
        }
    }
#undef SA
#undef SB
#undef DAx
#undef DBx
#undef MF
#undef MFMA16
#undef BAR
#undef SCHED0
#undef VMW4
}

// ---------- correct-but-slow fallback (only if ws too small) ----------

__global__ __launch_bounds__(256) void fallback_kernel(const float* __restrict__ x,
                                                       const int* __restrict__ wq,
                                                       const float* __restrict__ qscale,
                                                       const float* __restrict__ qzero,
                                                       const float* __restrict__ theta,
                                                       const void* __restrict__ maskp,
                                                       const float* __restrict__ bias,
                                                       float* __restrict__ out) {
    __shared__ float xs[64][17];
    __shared__ float wsh[64][17];
    const int mi32 = mask_is_int32(maskp);
    const int n0 = blockIdx.x * 64, m0 = blockIdx.y * 64;
    const int t = threadIdx.x;
    const int tr = t >> 4, tc = t & 15;
    float acc[4][4] = {};

    for (int k0 = 0; k0 < K_DIM; k0 += 16) {
#pragma unroll
        for (int j = 0; j < 4; ++j) {
            int e = t * 4 + j;
            int r = e >> 4, c = e & 15;
            xs[r][c] = x[(size_t)(m0 + r) * K_DIM + k0 + c];
            int o = n0 + r;
            size_t idx = (size_t)o * K_DIM + k0 + c;
            float dq = ((float)wq[idx] - qzero[o]) * qscale[o];
            int mv = mi32 ? ((const int*)maskp)[idx] : ((const unsigned char*)maskp)[idx];
            wsh[r][c] = mv ? dq : theta[idx];
        }
        __syncthreads();
#pragma unroll
        for (int kk = 0; kk < 16; ++kk) {
            float a4[4], b4[4];
#pragma unroll
            for (int i = 0; i < 4; ++i) a4[i] = xs[tr * 4 + i][kk];
#pragma unroll
            for (int i = 0; i < 4; ++i) b4[i] = wsh[tc * 4 + i][kk];
#pragma unroll
            for (int i = 0; i < 4; ++i)
#pragma unroll
                for (int j = 0; j < 4; ++j) acc[i][j] += a4[i] * b4[j];
        }
        __syncthreads();
    }
#pragma unroll
    for (int i = 0; i < 4; ++i)
#pragma unroll
        for (int j = 0; j < 4; ++j)
            out[(size_t)(m0 + tr * 4 + i) * N_OUT + n0 + tc * 4 + j] =
                acc[i][j] + bias[n0 + tc * 4 + j];
}

// ---------- launch ----------

extern "C" void kernel_launch(void* const* d_in, const int* in_sizes, int n_in,
                              void* d_out, int out_size, void* d_ws, size_t ws_size,
                              hipStream_t stream) {
    const float* x      = (const float*)d_in[0];
    const int*   wq     = (const int*)d_in[1];
    const float* qscale = (const float*)d_in[2];
    const float* qzero  = (const float*)d_in[3];
    const float* theta  = (const float*)d_in[4];
    const void*  mask   = d_in[5];
    const float* bias   = (const float*)d_in[6];
    float* out = (float*)d_out;

    const size_t xb_bytes = (size_t)M_ROWS * K_DIM * 2;
    const size_t wb_bytes = (size_t)N_OUT * K_DIM * 2;

    if (ws_size >= xb_bytes + wb_bytes) {
        u16* xb = (u16*)d_ws;
        u16* wb = (u16*)((char*)d_ws + xb_bytes);
        prep_kernel<<<24576, 256, 0, stream>>>(x, xb, wq, qscale, qzero, theta, mask, wb);
        dim3 grid(N_OUT / 256, M_ROWS / 256);
        gemm8_kernel<<<grid, 512, 0, stream>>>(xb, wb, bias, out);
    } else {
        dim3 grid(N_OUT / 64, M_ROWS / 64);
        fallback_kernel<<<grid, 256, 0, stream>>>(x, wq, qscale, qzero, theta, mask, bias, out);
    }
}